// Round 3
// baseline (545.362 us; speedup 1.0000x reference)
//
#include <hip/hip_runtime.h>
#include <hip/hip_bf16.h>

#define D 8196
#define H 4096
#define MLP_HID 32
#define OUT_N 130

typedef float vfloat4 __attribute__((ext_vector_type(4)));

__device__ __forceinline__ float sigmoidf_(float v) {
    return 1.0f / (1.0f + expf(-v));
}

__device__ __forceinline__ float dot4v(vfloat4 a, vfloat4 b) {
    return a.x * b.x + a.y * b.y + a.z * b.z + a.w * b.w;
}

__device__ __forceinline__ float wave_reduce(float acc) {
    #pragma unroll
    for (int off = 32; off > 0; off >>= 1)
        acc += __shfl_down(acc, off);
    return acc;
}

// 2048 blocks x 256 threads. Block b owns hidden units j0=2b, j0+1.
// Wave g (0..3) computes gate rows g*H+j0 and g*H+j0+1 (one x/h0 load
// amortized over two weight rows). Weights use nontemporal loads (stream-
// once). Last block (atomic counter) runs the MLP head after a device fence.
__global__ __launch_bounds__(256) void brain_fused_kernel(
    const float* __restrict__ x, const float* __restrict__ h0,
    const float* __restrict__ c0,
    const float* __restrict__ W_ih, const float* __restrict__ W_hh,
    const float* __restrict__ b_ih, const float* __restrict__ b_hh,
    const float* __restrict__ W1, const float* __restrict__ b1,
    const float* __restrict__ W2, const float* __restrict__ b2,
    float* __restrict__ out,
    unsigned int* __restrict__ counter, float* __restrict__ h_ws)
{
    const int g    = threadIdx.x >> 6;   // gate 0..3 (i,f,g,o)
    const int lane = threadIdx.x & 63;
    const int j0   = blockIdx.x * 2;
    const size_t r0 = (size_t)g * H + j0;

    float acc0 = 0.0f, acc1 = 0.0f;

    // ---- W_ih rows r0, r0+1 . x   (D/4 = 2049 float4s per row) ----
    {
        const vfloat4* __restrict__ A0 = (const vfloat4*)(W_ih + r0 * D);
        const vfloat4* __restrict__ A1 = (const vfloat4*)(W_ih + (r0 + 1) * D);
        const vfloat4* __restrict__ x4 = (const vfloat4*)x;
        #pragma unroll 4
        for (int it = 0; it < 32; ++it) {
            const int idx = it * 64 + lane;
            const vfloat4 xv = x4[idx];
            acc0 += dot4v(__builtin_nontemporal_load(&A0[idx]), xv);
            acc1 += dot4v(__builtin_nontemporal_load(&A1[idx]), xv);
        }
        if (lane == 0) {  // tail float4 (idx 2048)
            const vfloat4 xv = x4[2048];
            acc0 += dot4v(__builtin_nontemporal_load(&A0[2048]), xv);
            acc1 += dot4v(__builtin_nontemporal_load(&A1[2048]), xv);
        }
    }
    // ---- W_hh rows r0, r0+1 . h0  (H/4 = 1024 float4s per row) ----
    {
        const vfloat4* __restrict__ B0 = (const vfloat4*)(W_hh + r0 * H);
        const vfloat4* __restrict__ B1 = (const vfloat4*)(W_hh + (r0 + 1) * H);
        const vfloat4* __restrict__ h4 = (const vfloat4*)h0;
        #pragma unroll 4
        for (int it = 0; it < 16; ++it) {
            const int idx = it * 64 + lane;
            const vfloat4 hv = h4[idx];
            acc0 += dot4v(__builtin_nontemporal_load(&B0[idx]), hv);
            acc1 += dot4v(__builtin_nontemporal_load(&B1[idx]), hv);
        }
    }

    acc0 = wave_reduce(acc0);
    acc1 = wave_reduce(acc1);

    __shared__ float gate[4][2];
    __shared__ int lastflag;
    if (lane == 0) {
        gate[g][0] = acc0 + b_ih[r0]     + b_hh[r0];
        gate[g][1] = acc1 + b_ih[r0 + 1] + b_hh[r0 + 1];
    }
    __syncthreads();

    if (threadIdx.x < 2) {
        const int t = threadIdx.x;
        const int j = j0 + t;
        const float ig = sigmoidf_(gate[0][t]);
        const float fg = sigmoidf_(gate[1][t]);
        const float gg = tanhf(gate[2][t]);
        const float og = sigmoidf_(gate[3][t]);
        const float c  = fg * c0[j] + ig * gg;
        h_ws[j] = og * tanhf(c);
    }

    // Release h_ws device-wide, then count finished blocks.
    __threadfence();
    if (threadIdx.x == 0)
        lastflag = (atomicAdd(counter, 1u) == (unsigned)(gridDim.x - 1));
    __syncthreads();
    if (!lastflag) return;
    __threadfence();  // acquire: invalidate caches before reading h_ws

    // ---- MLP head (last block only): z = relu(W1@h+b1); out = sigmoid(W2@z+b2)
    __shared__ float z[MLP_HID];
    {
        const vfloat4* __restrict__ h4 = (const vfloat4*)h_ws;
        for (int r = g; r < MLP_HID; r += 4) {
            const vfloat4* __restrict__ Wr = (const vfloat4*)(W1 + (size_t)r * H);
            float acc = 0.0f;
            #pragma unroll 4
            for (int it = 0; it < 16; ++it) {
                const int idx = it * 64 + lane;
                acc += dot4v(Wr[idx], h4[idx]);
            }
            acc = wave_reduce(acc);
            if (lane == 0)
                z[r] = fmaxf(acc + b1[r], 0.0f);
        }
    }
    __syncthreads();

    if (threadIdx.x < OUT_N) {
        float acc = b2[threadIdx.x];
        #pragma unroll
        for (int k = 0; k < MLP_HID; ++k)
            acc += W2[threadIdx.x * MLP_HID + k] * z[k];
        out[threadIdx.x] = sigmoidf_(acc);
    }
}

extern "C" void kernel_launch(void* const* d_in, const int* in_sizes, int n_in,
                              void* d_out, int out_size, void* d_ws, size_t ws_size,
                              hipStream_t stream) {
    const float* x    = (const float*)d_in[0];
    const float* h0   = (const float*)d_in[1];
    const float* c0   = (const float*)d_in[2];
    const float* W_ih = (const float*)d_in[3];
    const float* W_hh = (const float*)d_in[4];
    const float* b_ih = (const float*)d_in[5];
    const float* b_hh = (const float*)d_in[6];
    const float* W1   = (const float*)d_in[7];
    const float* b1   = (const float*)d_in[8];
    const float* W2   = (const float*)d_in[9];
    const float* b2   = (const float*)d_in[10];
    float* out = (float*)d_out;

    // ws layout: [0..3] counter, [256B ...] h (H floats, 16B-aligned)
    unsigned int* counter = (unsigned int*)d_ws;
    float* h_ws = (float*)((char*)d_ws + 256);

    (void)hipMemsetAsync(counter, 0, sizeof(unsigned int), stream);
    brain_fused_kernel<<<H / 2, 256, 0, stream>>>(
        x, h0, c0, W_ih, W_hh, b_ih, b_hh, W1, b1, W2, b2, out, counter, h_ws);
}